// Round 1
// baseline (686.431 us; speedup 1.0000x reference)
//
#include <hip/hip_runtime.h>

typedef float vfloat4 __attribute__((ext_vector_type(4)));

#define TT 1024
#define BB 8
#define DD 16
#define NN 8192   // BB*TT

// ---------------- Kernel A: exact per-column median (bitonic sort in LDS) ---
__global__ __launch_bounds__(1024) void median_k(const float* __restrict__ v,
                                                 float* __restrict__ thr) {
    __shared__ float s[NN];
    const int d = blockIdx.x;
    for (int i = threadIdx.x; i < NN; i += 1024) s[i] = v[i * DD + d];
    __syncthreads();
    for (int k = 2; k <= NN; k <<= 1) {
        for (int j = k >> 1; j > 0; j >>= 1) {
            for (int i = threadIdx.x; i < NN; i += 1024) {
                int l = i ^ j;
                if (l > i) {
                    float a = s[i], b = s[l];
                    bool up = ((i & k) == 0);
                    if ((a > b) == up) { s[i] = b; s[l] = a; }
                }
            }
            __syncthreads();
        }
    }
    if (threadIdx.x == 0) thr[d] = 0.5f * (s[NN / 2 - 1] + s[NN / 2]);
}

// ---------------- Kernel B: per-(q,d) batch sums of m, m*z, m*z^2 -----------
__global__ __launch_bounds__(256) void colsum_k(const float* __restrict__ z,
                                                const float* __restrict__ v,
                                                const float* __restrict__ thr,
                                                float* __restrict__ ms,
                                                float* __restrict__ vs,
                                                float* __restrict__ us) {
    const int g = blockIdx.x * 256 + threadIdx.x;   // g = q*16 + d
    const int d = g & (DD - 1);
    const float t = thr[d];
    float sm = 0.f, sv = 0.f, su = 0.f;
#pragma unroll
    for (int b = 0; b < BB; ++b) {
        float vv = v[b * (TT * DD) + g];
        float zz = z[b * (TT * DD) + g];
        if (vv <= t) { sm += 1.f; sv += zz; su += zz * zz; }
    }
    ms[g] = sm; vs[g] = sv; us[g] = su;
}

// ---------------- Kernel C: quadratic forms vs Wt -> inv_ls2 per d ----------
// S_d = 2 * sum_p [ Us[p]*(Wt@ms)[p] - Vs[p]*(Wt@Vs)[p] ]
__global__ __launch_bounds__(1024) void scale_k(const float* __restrict__ ms,
                                                const float* __restrict__ vs,
                                                const float* __restrict__ us,
                                                const float* __restrict__ lsin,
                                                float* __restrict__ inv_out) {
    __shared__ float sm[TT], sv[TT], wt[TT], red[1024];
    const int d = blockIdx.x;
    const int p = threadIdx.x;
    sm[p] = ms[p * DD + d];
    sv[p] = vs[p * DD + d];
    wt[p] = 1.0f / ((float)p + 1e-6f);
    const float a = us[p * DD + d];
    __syncthreads();
    const float c = sv[p];
    float acc = 0.f;
#pragma unroll 4
    for (int q = 0; q < TT; ++q) {
        int ad = p - q; ad = ad < 0 ? -ad : ad;
        acc += wt[ad] * (a * sm[q] - c * sv[q]);
    }
    red[p] = acc;
    __syncthreads();
    for (int off = 512; off > 0; off >>= 1) {
        if (p < off) red[p] += red[p + off];
        __syncthreads();
    }
    const float S2 = 2.0f * red[0];
    __syncthreads();
    red[p] = sm[p];                      // n_d = sum_q ms[q,d]
    __syncthreads();
    for (int off = 512; off > 0; off >>= 1) {
        if (p < off) red[p] += red[p + off];
        __syncthreads();
    }
    if (p == 0) {
        const float n = red[0];
        float ls;
        if (n >= 2.0f) ls = sqrtf(S2 / (n * n));
        else           ls = expf(lsin[d]);
        inv_out[d] = 1.0f / (ls * ls);
    }
}

// ---------------- Kernel D: stream K out, replicated over b -----------------
// out[b][d][i][j] = exp(-(j-i)^2 * inv_ls2[d]); one block per (d,i) row.
__global__ __launch_bounds__(256) void write_k(const float* __restrict__ inv_ls2,
                                               float* __restrict__ out) {
    const int bid = blockIdx.x;
    const int d = bid >> 10;
    const int i = bid & (TT - 1);
    const float inv = inv_ls2[d];
    const int j0 = threadIdx.x * 4;
    vfloat4 val;
#pragma unroll
    for (int jj = 0; jj < 4; ++jj) {
        const int diff = (j0 + jj) - i;
        const float f = (float)(diff * diff);
        val[jj] = __expf(-f * inv);
    }
    const size_t base = ((size_t)d << 20) | ((size_t)i << 10) | (size_t)j0;
#pragma unroll
    for (int b = 0; b < BB; ++b) {
        vfloat4* p = (vfloat4*)(out + ((size_t)b << 24) + base);
        __builtin_nontemporal_store(val, p);
    }
}

extern "C" void kernel_launch(void* const* d_in, const int* in_sizes, int n_in,
                              void* d_out, int out_size, void* d_ws, size_t ws_size,
                              hipStream_t stream) {
    const float* z    = (const float*)d_in[0];
    const float* v    = (const float*)d_in[1];
    const float* lsin = (const float*)d_in[2];
    float* out = (float*)d_out;

    float* ws  = (float*)d_ws;
    float* thr = ws;                 // 16
    float* inv = ws + 16;            // 16
    float* ms  = ws + 32;            // 16384
    float* vs  = ms + TT * DD;       // 16384
    float* us  = vs + TT * DD;       // 16384

    median_k<<<DD, 1024, 0, stream>>>(v, thr);
    colsum_k<<<(TT * DD) / 256, 256, 0, stream>>>(z, v, thr, ms, vs, us);
    scale_k<<<DD, 1024, 0, stream>>>(ms, vs, us, lsin, inv);
    write_k<<<DD * TT, 256, 0, stream>>>(inv, out);
}

// Round 2
// 574.477 us; speedup vs baseline: 1.1949x; 1.1949x over previous
//
#include <hip/hip_runtime.h>

typedef float vfloat4 __attribute__((ext_vector_type(4)));

#define TT 1024
#define BB 8
#define DD 16
#define NN 8192   // BB*TT

__device__ inline float untr(unsigned u) {
    unsigned b = (u & 0x80000000u) ? (u & 0x7fffffffu) : ~u;
    return __uint_as_float(b);
}

// ---------------- Kernel A: exact per-column median via 3-pass radix select -
// rank 4095 by MSB-first radix descent (11/11/10 bits); rank 4096 via one
// extra pass (count<=A, min of keys>A). thr = midpoint.
__global__ __launch_bounds__(1024) void median_k(const float* __restrict__ v,
                                                 float* __restrict__ thr) {
    __shared__ unsigned key[NN];      // 32 KB
    __shared__ unsigned hist[2048];   // 8 KB
    __shared__ unsigned wsum[16];
    __shared__ unsigned found_bin, found_cum;
    __shared__ unsigned s_cle, s_min;
    const int d = blockIdx.x;
    const int tid = threadIdx.x;
    const int wid = tid >> 6, lane = tid & 63;

    for (int i = tid; i < NN; i += 1024) {
        unsigned b = __float_as_uint(v[i * DD + d]);
        key[i] = (b & 0x80000000u) ? ~b : (b | 0x80000000u);  // order-preserving
    }
    if (tid == 0) { s_cle = 0; s_min = 0xFFFFFFFFu; }
    __syncthreads();

    unsigned prefix = 0;
    unsigned r = 4095;            // 0-based rank of lower middle
    int matched_bits = 0;
    int shift = 32;
    const int chunk_bits[3] = {11, 11, 10};
#pragma unroll
    for (int pass = 0; pass < 3; ++pass) {
        const int bits = chunk_bits[pass];
        shift -= bits;
        const int nb = 1 << bits;
        hist[tid] = 0; hist[tid + 1024] = 0;
        __syncthreads();
        for (int i = tid; i < NN; i += 1024) {
            unsigned k = key[i];
            if (matched_bits == 0 || (k >> (shift + bits)) == prefix)
                atomicAdd(&hist[(k >> shift) & (unsigned)(nb - 1)], 1u);
        }
        __syncthreads();
        // find bin where cumulative count crosses r (pair-per-thread + scans)
        unsigned h0 = 0, h1 = 0, s2 = 0;
        if (tid < nb / 2) { h0 = hist[2 * tid]; h1 = hist[2 * tid + 1]; s2 = h0 + h1; }
        unsigned inc = s2;
        for (int o = 1; o < 64; o <<= 1) {
            unsigned t = __shfl_up(inc, o);
            if (lane >= o) inc += t;
        }
        if (lane == 63) wsum[wid] = inc;
        __syncthreads();
        if (tid < 16) {
            unsigned x = wsum[tid], ix = x;
            for (int o = 1; o < 16; o <<= 1) {
                unsigned t = __shfl_up(ix, o);
                if (lane >= o) ix += t;
            }
            wsum[tid] = ix - x;   // exclusive wave offsets
        }
        __syncthreads();
        if (tid < nb / 2) {
            unsigned cum = wsum[wid] + (inc - s2);     // count before bin 2*tid
            if (r >= cum && r < cum + h0)            { found_bin = 2u * tid;     found_cum = cum; }
            else if (r >= cum + h0 && r < cum + s2)  { found_bin = 2u * tid + 1; found_cum = cum + h0; }
        }
        __syncthreads();
        prefix = (prefix << bits) | found_bin;
        r -= found_cum;
        matched_bits += bits;
    }
    const unsigned A = prefix;     // key of s[4095]

    // second order stat: c_le = #keys<=A ; mg = min key > A
    unsigned cle = 0, mg = 0xFFFFFFFFu;
    for (int i = tid; i < NN; i += 1024) {
        unsigned k = key[i];
        if (k <= A) cle++;
        else mg = min(mg, k);
    }
    for (int o = 32; o; o >>= 1) {
        cle += __shfl_xor(cle, o);
        mg = min(mg, (unsigned)__shfl_xor(mg, o));
    }
    if (lane == 0) { atomicAdd(&s_cle, cle); atomicMin(&s_min, mg); }
    __syncthreads();
    if (tid == 0) {
        unsigned Bk = (s_cle >= 4097u) ? A : s_min;   // s[4096]
        thr[d] = 0.5f * (untr(A) + untr(Bk));
    }
}

// ---------------- Kernel B: per-(q,d) batch sums of m, m*z, m*z^2 -----------
__global__ __launch_bounds__(256) void colsum_k(const float* __restrict__ z,
                                                const float* __restrict__ v,
                                                const float* __restrict__ thr,
                                                float* __restrict__ ms,
                                                float* __restrict__ vs,
                                                float* __restrict__ us,
                                                float* __restrict__ Sacc,
                                                float* __restrict__ nacc) {
    const int g = blockIdx.x * 256 + threadIdx.x;   // g = q*16 + d
    if (blockIdx.x == 0) {                           // zero accumulators for scale_k
        if (threadIdx.x < DD)            Sacc[threadIdx.x] = 0.f;
        else if (threadIdx.x < 2 * DD)   nacc[threadIdx.x - DD] = 0.f;
    }
    const int d = g & (DD - 1);
    const float t = thr[d];
    float sm = 0.f, sv = 0.f, su = 0.f;
#pragma unroll
    for (int b = 0; b < BB; ++b) {
        float vv = v[b * (TT * DD) + g];
        float zz = z[b * (TT * DD) + g];
        if (vv <= t) { sm += 1.f; sv += zz; su += zz * zz; }
    }
    ms[g] = sm; vs[g] = sv; us[g] = su;
}

// ---------------- Kernel C: quadratic forms vs Wt (Toeplitz) ----------------
// grid = DD*16 blocks, 64 threads; block handles d = bid>>4, p-chunk bid&15.
__global__ __launch_bounds__(64) void scale_k(const float* __restrict__ ms,
                                              const float* __restrict__ vs,
                                              const float* __restrict__ us,
                                              float* __restrict__ Sacc,
                                              float* __restrict__ nacc) {
    __shared__ float sm[TT], sv[TT], wt[TT];
    const int d = blockIdx.x >> 4;
    const int chunk = blockIdx.x & 15;
    const int tid = threadIdx.x;
    for (int q = tid; q < TT; q += 64) {
        sm[q] = ms[q * DD + d];
        sv[q] = vs[q * DD + d];
        wt[q] = 1.0f / ((float)q + 1e-6f);
    }
    __syncthreads();
    const int p = chunk * 64 + tid;
    const float a = us[p * DD + d];
    const float c = sv[p];
    float acc = 0.f;
#pragma unroll 4
    for (int q = 0; q < TT; ++q) {
        int ad = p - q; ad = ad < 0 ? -ad : ad;
        acc = fmaf(wt[ad], fmaf(a, sm[q], -(c * sv[q])), acc);
    }
    float npart = sm[p];
    for (int o = 32; o; o >>= 1) {
        acc += __shfl_xor(acc, o);
        npart += __shfl_xor(npart, o);
    }
    if (tid == 0) {
        atomicAdd(&Sacc[d], 2.0f * acc);
        atomicAdd(&nacc[d], npart);
    }
}

// ---------------- Kernel C2: finalize inv_ls2 per d -------------------------
__global__ __launch_bounds__(64) void ls_k(const float* __restrict__ Sacc,
                                           const float* __restrict__ nacc,
                                           const float* __restrict__ lsin,
                                           float* __restrict__ inv_out) {
    const int d = threadIdx.x;
    if (d < DD) {
        const float n = nacc[d], S = Sacc[d];
        float invv;
        if (n >= 2.0f) invv = (n * n) / S;            // 1/ls^2 = n^2/S
        else { const float e = expf(lsin[d]); invv = 1.0f / (e * e); }
        inv_out[d] = invv;
    }
}

// ---------------- Kernel D: stream K out, replicated over b -----------------
__global__ __launch_bounds__(256) void write_k(const float* __restrict__ inv_ls2,
                                               float* __restrict__ out) {
    const int bid = blockIdx.x;
    const int d = bid >> 10;
    const int i = bid & (TT - 1);
    const float inv = inv_ls2[d];
    const int j0 = threadIdx.x * 4;
    vfloat4 val;
#pragma unroll
    for (int jj = 0; jj < 4; ++jj) {
        const int diff = (j0 + jj) - i;
        const float f = (float)(diff * diff);
        val[jj] = __expf(-f * inv);
    }
    const size_t base = ((size_t)d << 20) | ((size_t)i << 10) | (size_t)j0;
#pragma unroll
    for (int b = 0; b < BB; ++b) {
        vfloat4* p = (vfloat4*)(out + ((size_t)b << 24) + base);
        __builtin_nontemporal_store(val, p);
    }
}

extern "C" void kernel_launch(void* const* d_in, const int* in_sizes, int n_in,
                              void* d_out, int out_size, void* d_ws, size_t ws_size,
                              hipStream_t stream) {
    const float* z    = (const float*)d_in[0];
    const float* v    = (const float*)d_in[1];
    const float* lsin = (const float*)d_in[2];
    float* out = (float*)d_out;

    float* ws   = (float*)d_ws;
    float* thr  = ws;                 // 16
    float* inv  = ws + 16;            // 16
    float* Sacc = ws + 32;            // 16
    float* nacc = ws + 48;            // 16
    float* ms   = ws + 64;            // 16384
    float* vs   = ms + TT * DD;       // 16384
    float* us   = vs + TT * DD;       // 16384

    median_k<<<DD, 1024, 0, stream>>>(v, thr);
    colsum_k<<<(TT * DD) / 256, 256, 0, stream>>>(z, v, thr, ms, vs, us, Sacc, nacc);
    scale_k<<<DD * 16, 64, 0, stream>>>(ms, vs, us, Sacc, nacc);
    ls_k<<<1, 64, 0, stream>>>(Sacc, nacc, lsin, inv);
    write_k<<<DD * TT, 256, 0, stream>>>(inv, out);
}